// Round 1
// baseline (653.973 us; speedup 1.0000x reference)
//
#include <hip/hip_runtime.h>
#include <hip/hip_bf16.h>

typedef __bf16 bf16;
typedef __bf16 bf16x8 __attribute__((ext_vector_type(8)));
typedef __bf16 bf16x4 __attribute__((ext_vector_type(4)));
typedef float f32x4 __attribute__((ext_vector_type(4)));

#define MFMA16(a, b, c) __builtin_amdgcn_mfma_f32_16x16x32_bf16((a), (b), (c), 0, 0, 0)

// ---- problem constants ----
static constexpr int Hh = 128, Ww = 128;
// ws layout (bytes)
static constexpr size_t FEAT_OFF = 0;                   // 4,194,304 bf16 = 8,388,608 B
static constexpr size_t OMW_OFF  = 8388608;             // 995,328 bf16  = 1,990,656 B
static constexpr size_t OMB_OFF  = OMW_OFF + 1990656;   // 1728 f32      = 6,912 B
static constexpr size_t DCW_OFF  = OMB_OFF + 6912;      // 36,864 bf16   = 73,728 B

// ---------------- prep kernels ----------------
__global__ void prep_cvt(const float* __restrict__ in, bf16* __restrict__ out, int n) {
    int i = blockIdx.x * 256 + threadIdx.x;
    if (i < n) out[i] = (bf16)in[i];
}

// om_w [ch=1728][cf=64][ky=3][kx=3] fp32  ->  om_w_r [m'=type*576+ck][k'=tap*64+cf] bf16
// ch(type,ck): type<2 -> ck*2+type (y/x interleaved), type==2 -> 1152+ck
__global__ void prep_w(const float* __restrict__ om_w, const float* __restrict__ om_b,
                       bf16* __restrict__ om_w_r, float* __restrict__ om_b_r) {
    int i = blockIdx.x * 256 + threadIdx.x;
    if (i < 1728 * 576) {
        int m = i / 576, k = i - m * 576;
        int t = m / 576, ck = m - t * 576;
        int ch = (t < 2) ? (ck * 2 + t) : (1152 + ck);
        int tap = k >> 6, cf = k & 63;
        om_w_r[i] = (bf16)om_w[ch * 576 + cf * 9 + tap];
    }
    if (i < 1728) {
        int t = i / 576, ck = i - t * 576;
        int ch = (t < 2) ? (ck * 2 + t) : (1152 + ck);
        om_b_r[i] = om_b[ch];
    }
}

// ---------------- fused main kernel ----------------
// One workgroup per (b, h): 256 threads = 4 waves.
// GEMM1: off_msk rows for ck-block (64 cks x 3 types) = om_w_r @ im2col(feat)  [MFMA bf16]
// sample: bilinear gather from fp32 inputs, * sigmoid(mask)
// GEMM2: out[64o][128px] += dc_w[o][ck] * sampled  (B-frag straight from GEMM1 C-layout)

__device__ __forceinline__ void process_block(
    int blk, int b, int h, int wid, int l15, int g,
    const bf16* __restrict__ featp, const float* __restrict__ inputs,
    const bf16* __restrict__ omwr, const float* __restrict__ ombr,
    bf16x4* pout)
{
    const int ck0 = blk * 64;
    f32x4 acc1[3][8];
#pragma unroll
    for (int t = 0; t < 3; ++t)
#pragma unroll
        for (int nf = 0; nf < 8; ++nf) acc1[t][nf] = (f32x4){0.f, 0.f, 0.f, 0.f};

    const int arow = ck0 + wid * 16 + l15;
    const bf16* ar0 = omwr + (size_t)(0 * 576 + arow) * 576;
    const bf16* ar1 = omwr + (size_t)(1 * 576 + arow) * 576;
    const bf16* ar2 = omwr + (size_t)(2 * 576 + arow) * 576;

#pragma unroll 2
    for (int kk = 0; kk < 18; ++kk) {
        const int koff = kk * 32 + g * 8;
        bf16x8 a0 = *(const bf16x8*)(ar0 + koff);
        bf16x8 a1 = *(const bf16x8*)(ar1 + koff);
        bf16x8 a2 = *(const bf16x8*)(ar2 + koff);
        const int tap = kk >> 1;
        const int kyp = tap / 3, kxp = tap - 3 * kyp;
        const int base = (kyp * 130 + kxp + l15) * 72 + (kk & 1) * 32 + g * 8;
#pragma unroll
        for (int nf = 0; nf < 8; ++nf) {
            bf16x8 bfr = *(const bf16x8*)(featp + base + nf * 16 * 72);
            acc1[0][nf] = MFMA16(a0, bfr, acc1[0][nf]);
            acc1[1][nf] = MFMA16(a1, bfr, acc1[1][nf]);
            acc1[2][nf] = MFMA16(a2, bfr, acc1[2][nf]);
        }
    }

    // per-reg constants (ck -> c, dy, dx, biases)
    int cpl[4], dyv[4], dxv[4];
    float by[4], bx[4], bm[4];
#pragma unroll
    for (int r = 0; r < 4; ++r) {
        int ck = ck0 + wid * 16 + g * 4 + r;
        int c = ck / 9, kd = ck - 9 * c;
        int kq = kd / 3;
        cpl[r] = c; dyv[r] = kq - 1; dxv[r] = kd - 3 * kq - 1;
        by[r] = ombr[ck]; bx[r] = ombr[576 + ck]; bm[r] = ombr[1152 + ck];
    }

#pragma unroll
    for (int nf = 0; nf < 8; ++nf) {
        float s[4];
#pragma unroll
        for (int r = 0; r < 4; ++r) {
            float offy = acc1[0][nf][r] + by[r];
            float offx = acc1[1][nf][r] + bx[r];
            float lg   = acc1[2][nf][r] + bm[r];
            float py = (float)(h + dyv[r]) + offy;
            float px = (float)(nf * 16 + l15 + dxv[r]) + offx;
            float y0f = floorf(py), x0f = floorf(px);
            float wy = py - y0f, wx = px - x0f;
            int y0 = (int)y0f, x0 = (int)x0f;
            int y1 = y0 + 1, x1 = x0 + 1;
            const float* pl = inputs + ((size_t)(b * 64 + cpl[r]) << 14);
            int y0c = min(max(y0, 0), 127), y1c = min(max(y1, 0), 127);
            int x0c = min(max(x0, 0), 127), x1c = min(max(x1, 0), 127);
            bool vy0 = (unsigned)y0 < 128u, vy1 = (unsigned)y1 < 128u;
            bool vx0 = (unsigned)x0 < 128u, vx1 = (unsigned)x1 < 128u;
            float v00 = (vy0 && vx0) ? pl[(y0c << 7) + x0c] : 0.f;
            float v01 = (vy0 && vx1) ? pl[(y0c << 7) + x1c] : 0.f;
            float v10 = (vy1 && vx0) ? pl[(y1c << 7) + x0c] : 0.f;
            float v11 = (vy1 && vx1) ? pl[(y1c << 7) + x1c] : 0.f;
            float bil = (1.f - wy) * ((1.f - wx) * v00 + wx * v01)
                      + wy * ((1.f - wx) * v10 + wx * v11);
            float msk = __builtin_amdgcn_rcpf(1.f + __expf(-lg));
            s[r] = bil * msk;
        }
        bf16x4 p = {(bf16)s[0], (bf16)s[1], (bf16)s[2], (bf16)s[3]};
        pout[nf] = p;
    }
}

__device__ __forceinline__ void gemm2_step(
    int ckA0w, int ckB0w, int l15, int g,
    const bf16* __restrict__ dcbf, const bf16x4* pA, const bf16x4* pB,
    f32x4 acc2[4][8])
{
#pragma unroll
    for (int t = 0; t < 4; ++t) {
        const bf16* wrow = dcbf + (size_t)(t * 16 + l15) * 576;
        bf16x4 aA = *(const bf16x4*)(wrow + ckA0w + g * 4);
        bf16x4 aB = *(const bf16x4*)(wrow + ckB0w + g * 4);
        bf16x8 afr = __builtin_shufflevector(aA, aB, 0, 1, 2, 3, 4, 5, 6, 7);
#pragma unroll
        for (int nf = 0; nf < 8; ++nf) {
            bf16x8 bfr = __builtin_shufflevector(pA[nf], pB[nf], 0, 1, 2, 3, 4, 5, 6, 7);
            acc2[t][nf] = MFMA16(afr, bfr, acc2[t][nf]);
        }
    }
}

__global__ void __launch_bounds__(256)
deform_fused(const float* __restrict__ inputs,
             const bf16* __restrict__ featbf,
             const bf16* __restrict__ omwr,
             const float* __restrict__ ombr,
             const bf16* __restrict__ dcbf,
             const float* __restrict__ dcb,
             float* __restrict__ out)
{
    const int bh = blockIdx.x;
    const int b = bh >> 7, h = bh & 127;
    const int tid = threadIdx.x;
    const int lane = tid & 63, wid = tid >> 6;
    const int l15 = lane & 15, g = lane >> 4;

    // feat patch [ky 3][col 130][cf 72-padded] bf16 = 56,160 B; overlaid by 64x128 f32 epilogue buf
    __shared__ __align__(16) unsigned char smem[3 * 130 * 72 * 2];
    bf16* featp = (bf16*)smem;
    float* outred = (float*)smem;

    // zero + stage feat patch (zero pad: OOB rows/cols stay 0)
    for (int i = tid; i < 14040; i += 256) ((unsigned*)smem)[i] = 0u;
    __syncthreads();
    if (tid < 192) {
        const int ky = tid >> 6, cf = tid & 63;
        const int hh = h - 1 + ky;
        if ((unsigned)hh < 128u) {
            const bf16* src = featbf + (size_t)((b * 64 + cf) * 128 + hh) * 128;
            for (int c0 = 0; c0 < 128; c0 += 8) {
                bf16x8 v = *(const bf16x8*)(src + c0);
#pragma unroll
                for (int e = 0; e < 8; ++e)
                    featp[(ky * 130 + c0 + e + 1) * 72 + cf] = v[e];
            }
        }
    }
    __syncthreads();

    f32x4 acc2[4][8];
#pragma unroll
    for (int t = 0; t < 4; ++t)
#pragma unroll
        for (int nf = 0; nf < 8; ++nf) acc2[t][nf] = (f32x4){0.f, 0.f, 0.f, 0.f};

    bf16x4 pA[8], pB[8];
    for (int pair = 0; pair < 4; ++pair) {
        process_block(2 * pair,     b, h, wid, l15, g, featp, inputs, omwr, ombr, pA);
        process_block(2 * pair + 1, b, h, wid, l15, g, featp, inputs, omwr, ombr, pB);
        gemm2_step(2 * pair * 64 + wid * 16, (2 * pair + 1) * 64 + wid * 16,
                   l15, g, dcbf, pA, pB, acc2);
    }
    // tail block 8: B-half zero (A-half junk x 0 is fine)
    process_block(8, b, h, wid, l15, g, featp, inputs, omwr, ombr, pA);
    {
        const bf16 z = (bf16)0.f;
        bf16x4 zz = {z, z, z, z};
#pragma unroll
        for (int nf = 0; nf < 8; ++nf) pB[nf] = zz;
    }
    gemm2_step(8 * 64 + wid * 16, 0, l15, g, dcbf, pA, pB, acc2);

    // ---- cross-wave reduce in LDS (overlay on feat patch) ----
    __syncthreads();
    if (wid == 0) {
#pragma unroll
        for (int t = 0; t < 4; ++t)
#pragma unroll
            for (int nf = 0; nf < 8; ++nf)
#pragma unroll
                for (int r = 0; r < 4; ++r)
                    outred[(t * 16 + g * 4 + r) * 128 + nf * 16 + l15] = acc2[t][nf][r];
    }
    __syncthreads();
    for (int w = 1; w < 4; ++w) {
        if (wid == w) {
#pragma unroll
            for (int t = 0; t < 4; ++t)
#pragma unroll
                for (int nf = 0; nf < 8; ++nf)
#pragma unroll
                    for (int r = 0; r < 4; ++r)
                        outred[(t * 16 + g * 4 + r) * 128 + nf * 16 + l15] += acc2[t][nf][r];
        }
        __syncthreads();
    }
    for (int i = tid; i < 8192; i += 256) {
        int o = i >> 7, px = i & 127;
        float v = outred[i] + dcb[o];
        out[(size_t)((b * 64 + o) * 128 + h) * 128 + px] = fmaxf(v, 0.f);
    }
}

// ---------------- launcher ----------------
extern "C" void kernel_launch(void* const* d_in, const int* in_sizes, int n_in,
                              void* d_out, int out_size, void* d_ws, size_t ws_size,
                              hipStream_t stream) {
    const float* inputs = (const float*)d_in[0];
    const float* feat   = (const float*)d_in[1];
    const float* om_w   = (const float*)d_in[2];
    const float* om_b   = (const float*)d_in[3];
    const float* dc_w   = (const float*)d_in[4];
    const float* dc_b   = (const float*)d_in[5];
    float* out = (float*)d_out;

    char* ws = (char*)d_ws;
    bf16*  featbf = (bf16*)(ws + FEAT_OFF);
    bf16*  omwr   = (bf16*)(ws + OMW_OFF);
    float* ombr   = (float*)(ws + OMB_OFF);
    bf16*  dcbf   = (bf16*)(ws + DCW_OFF);

    prep_cvt<<<(4194304 + 255) / 256, 256, 0, stream>>>(feat, featbf, 4194304);
    prep_w<<<(995328 + 255) / 256, 256, 0, stream>>>(om_w, om_b, omwr, ombr);
    prep_cvt<<<(36864 + 255) / 256, 256, 0, stream>>>(dc_w, dcbf, 36864);

    deform_fused<<<512, 256, 0, stream>>>(inputs, featbf, omwr, ombr, dcbf, dc_b, out);
}

// Round 2
// 219.576 us; speedup vs baseline: 2.9783x; 2.9783x over previous
//
#include <hip/hip_runtime.h>
#include <hip/hip_bf16.h>

typedef __bf16 bf16;
typedef __bf16 bf16x8 __attribute__((ext_vector_type(8)));
typedef __bf16 bf16x4 __attribute__((ext_vector_type(4)));
typedef float f32x4 __attribute__((ext_vector_type(4)));

#define MFMA16(a, b, c) __builtin_amdgcn_mfma_f32_16x16x32_bf16((a), (b), (c), 0, 0, 0)

// ws layout (bytes)
static constexpr size_t FEAT_OFF = 0;                   // 4,194,304 bf16
static constexpr size_t OMW_OFF  = 8388608;             // 995,328 bf16
static constexpr size_t OMB_OFF  = OMW_OFF + 1990656;   // 1728 f32
static constexpr size_t DCW_OFF  = OMB_OFF + 6912;      // 36,864 bf16

// ---------------- prep kernels ----------------
__global__ void prep_cvt(const float* __restrict__ in, bf16* __restrict__ out, int n) {
    int i = blockIdx.x * 256 + threadIdx.x;
    if (i < n) out[i] = (bf16)in[i];
}

// om_w [ch=1728][cf=64][3][3] fp32 -> om_w_r [m'=type*576+ck][k'=tap*64+cf] bf16
__global__ void prep_w(const float* __restrict__ om_w, const float* __restrict__ om_b,
                       bf16* __restrict__ om_w_r, float* __restrict__ om_b_r) {
    int i = blockIdx.x * 256 + threadIdx.x;
    if (i < 1728 * 576) {
        int m = i / 576, k = i - m * 576;
        int t = m / 576, ck = m - t * 576;
        int ch = (t < 2) ? (ck * 2 + t) : (1152 + ck);
        int tap = k >> 6, cf = k & 63;
        om_w_r[i] = (bf16)om_w[ch * 576 + cf * 9 + tap];
    }
    if (i < 1728) {
        int t = i / 576, ck = i - t * 576;
        int ch = (t < 2) ? (ck * 2 + t) : (1152 + ck);
        om_b_r[i] = om_b[ch];
    }
}

// ---------------- fused main kernel ----------------
// One workgroup per (b,h): 4 waves.
// LDS: feat patch, XOR-swizzled [ky 3][pc 130] rows of 128B (64 cf)  = 49,920 B
//      sampled exchange,         [pxl 64] rows of 128B (64 ck)       =  8,192 B
// Per 64-ck block: GEMM1 (MFMA, each wave 16 cks x 3 types x 128 px) -> sample
// (bilinear+mask) -> sampled to LDS (bf16) -> GEMM2 (each wave 16 o x 128 px,
// acc2 = 32 VGPRs, accumulated over all 9 blocks) -> direct store.

__global__ void __launch_bounds__(256, 2)
deform_fused(const float* __restrict__ inputs,
             const bf16* __restrict__ featbf,
             const bf16* __restrict__ omwr,
             const float* __restrict__ ombr,
             const bf16* __restrict__ dcbf,
             const float* __restrict__ dcb,
             float* __restrict__ out)
{
    const int bh = blockIdx.x;
    const int b = bh >> 7, h = bh & 127;
    const int tid = threadIdx.x;
    const int lane = tid & 63, wid = tid >> 6;
    const int l15 = lane & 15, g = lane >> 4;

    __shared__ __align__(16) unsigned char smem[49920 + 8192];
    char* featB = (char*)smem;           // swizzled feat patch
    char* sampB = (char*)smem + 49920;   // swizzled sampled exchange

    // zero feat patch (pads must be 0)
    for (int i = tid; i < 12480; i += 256) ((unsigned*)featB)[i] = 0u;
    __syncthreads();
    // stage feat rows h-1..h+1 ; logical (ky, pc, cf) ->
    //   byte = (ky*130+pc)*128 + (((cf>>3) ^ (pc&7))<<4) + (cf&7)*2
    if (tid < 192) {
        const int ky = tid >> 6, cf = tid & 63;
        const int hh = h - 1 + ky;
        if ((unsigned)hh < 128u) {
            const bf16* src = featbf + (size_t)((b * 64 + cf) * 128 + hh) * 128;
            const int cfb = cf >> 3, cfl = (cf & 7) << 1;
            for (int c0 = 0; c0 < 128; c0 += 8) {
                bf16x8 v = *(const bf16x8*)(src + c0);
#pragma unroll
                for (int e = 0; e < 8; ++e) {
                    int pc = c0 + e + 1;
                    *(bf16*)(featB + (ky * 130 + pc) * 128 + ((cfb ^ (pc & 7)) << 4) + cfl) = v[e];
                }
            }
        }
    }
    __syncthreads();

    f32x4 acc2[8];
#pragma unroll
    for (int nf = 0; nf < 8; ++nf) acc2[nf] = (f32x4){0.f, 0.f, 0.f, 0.f};

    const bf16* dcrow = dcbf + (size_t)(wid * 16 + l15) * 576;  // GEMM2 A row (o = wid*16+l15)

    for (int blk = 0; blk < 9; ++blk) {
        // ---- GEMM1: off/mask rows for this wave's 16 cks ----
        f32x4 acc1[3][8];
#pragma unroll
        for (int t = 0; t < 3; ++t)
#pragma unroll
            for (int nf = 0; nf < 8; ++nf) acc1[t][nf] = (f32x4){0.f, 0.f, 0.f, 0.f};

        const int arow = blk * 64 + wid * 16 + l15;
        const bf16* ar0 = omwr + (size_t)arow * 576;
        const bf16* ar1 = omwr + (size_t)(576 + arow) * 576;
        const bf16* ar2 = omwr + (size_t)(1152 + arow) * 576;

#pragma unroll 2
        for (int kk = 0; kk < 18; ++kk) {
            const int koff = kk * 32 + g * 8;
            bf16x8 a0 = *(const bf16x8*)(ar0 + koff);
            bf16x8 a1 = *(const bf16x8*)(ar1 + koff);
            bf16x8 a2 = *(const bf16x8*)(ar2 + koff);
            const int tap = kk >> 1;
            const int kyp = tap / 3, kxp = tap - 3 * kyp;
            const int base = (kyp * 130 + kxp + l15) * 128
                           + ((((kk & 1) * 4 + g) ^ ((l15 + kxp) & 7)) << 4);
#pragma unroll
            for (int nf = 0; nf < 8; ++nf) {
                bf16x8 bfr = *(const bf16x8*)(featB + base + nf * 2048);
                acc1[0][nf] = MFMA16(a0, bfr, acc1[0][nf]);
                acc1[1][nf] = MFMA16(a1, bfr, acc1[1][nf]);
                acc1[2][nf] = MFMA16(a2, bfr, acc1[2][nf]);
            }
        }

        // per-r constants (ck -> c, dy, dx, biases)
        int cpl[4], dyv[4], dxv[4];
        float by[4], bx[4], bm[4];
#pragma unroll
        for (int r = 0; r < 4; ++r) {
            int ck = blk * 64 + wid * 16 + g * 4 + r;
            int c = ck / 9, kd = ck - 9 * c, kq = kd / 3;
            cpl[r] = c; dyv[r] = kq - 1; dxv[r] = kd - 3 * kq - 1;
            by[r] = ombr[ck]; bx[r] = ombr[576 + ck]; bm[r] = ombr[1152 + ck];
        }

        // GEMM2 A-frags for this blk (shared by both halves)
        bf16x8 aK0 = *(const bf16x8*)(dcrow + blk * 64 + g * 8);
        bf16x8 aK1 = *(const bf16x8*)(dcrow + blk * 64 + 32 + g * 8);

#pragma unroll
        for (int half = 0; half < 2; ++half) {
            // sample 4 nf-tiles, write bf16x4 to sampled LDS
#pragma unroll
            for (int u = 0; u < 4; ++u) {
                const int nf = half * 4 + u;
                float s[4];
#pragma unroll
                for (int r = 0; r < 4; ++r) {
                    float offy = acc1[0][nf][r] + by[r];
                    float offx = acc1[1][nf][r] + bx[r];
                    float lg   = acc1[2][nf][r] + bm[r];
                    float py = (float)(h + dyv[r]) + offy;
                    float px = (float)(nf * 16 + l15 + dxv[r]) + offx;
                    float y0f = floorf(py), x0f = floorf(px);
                    float wy = py - y0f, wx = px - x0f;
                    int y0 = (int)y0f, x0 = (int)x0f;
                    int y1 = y0 + 1, x1 = x0 + 1;
                    const float* pl = inputs + ((size_t)(b * 64 + cpl[r]) << 14);
                    int y0c = min(max(y0, 0), 127), y1c = min(max(y1, 0), 127);
                    int x0c = min(max(x0, 0), 127), x1c = min(max(x1, 0), 127);
                    bool vy0 = (unsigned)y0 < 128u, vy1 = (unsigned)y1 < 128u;
                    bool vx0 = (unsigned)x0 < 128u, vx1 = (unsigned)x1 < 128u;
                    float v00 = (vy0 && vx0) ? pl[(y0c << 7) + x0c] : 0.f;
                    float v01 = (vy0 && vx1) ? pl[(y0c << 7) + x1c] : 0.f;
                    float v10 = (vy1 && vx0) ? pl[(y1c << 7) + x0c] : 0.f;
                    float v11 = (vy1 && vx1) ? pl[(y1c << 7) + x1c] : 0.f;
                    float bil = (1.f - wy) * ((1.f - wx) * v00 + wx * v01)
                              + wy * ((1.f - wx) * v10 + wx * v11);
                    float msk = __builtin_amdgcn_rcpf(1.f + __expf(-lg));
                    s[r] = bil * msk;
                }
                bf16x4 p = {(bf16)s[0], (bf16)s[1], (bf16)s[2], (bf16)s[3]};
                // (pxl = u*16+l15, ck = wid*16+g*4) ; 8B-block swizzle: cb ^= 2*(pxl&7)
                *(bf16x4*)(sampB + (u * 16 + l15) * 128
                           + (((wid * 4 + g) ^ ((l15 & 7) << 1)) << 3)) = p;
            }
            __syncthreads();
            // GEMM2 on this half's 64 px rows
#pragma unroll
            for (int u = 0; u < 4; ++u) {
                const int nf = half * 4 + u;
                const int rb = (u * 16 + l15) * 128;
                bf16x8 b0 = *(const bf16x8*)(sampB + rb + ((g ^ (l15 & 7)) << 4));
                bf16x8 b1 = *(const bf16x8*)(sampB + rb + (((4 + g) ^ (l15 & 7)) << 4));
                acc2[nf] = MFMA16(aK0, b0, acc2[nf]);
                acc2[nf] = MFMA16(aK1, b1, acc2[nf]);
            }
            __syncthreads();
        }
    }

    // ---- epilogue: bias + relu, direct stores (o = wid*16+g*4+r, px = nf*16+l15)
    float bias[4];
#pragma unroll
    for (int r = 0; r < 4; ++r) bias[r] = dcb[wid * 16 + g * 4 + r];
#pragma unroll
    for (int nf = 0; nf < 8; ++nf)
#pragma unroll
        for (int r = 0; r < 4; ++r) {
            int o = wid * 16 + g * 4 + r;
            out[(size_t)((b * 64 + o) * 128 + h) * 128 + nf * 16 + l15]
                = fmaxf(acc2[nf][r] + bias[r], 0.f);
        }
}

// ---------------- launcher ----------------
extern "C" void kernel_launch(void* const* d_in, const int* in_sizes, int n_in,
                              void* d_out, int out_size, void* d_ws, size_t ws_size,
                              hipStream_t stream) {
    const float* inputs = (const float*)d_in[0];
    const float* feat   = (const float*)d_in[1];
    const float* om_w   = (const float*)d_in[2];
    const float* om_b   = (const float*)d_in[3];
    const float* dc_w   = (const float*)d_in[4];
    const float* dc_b   = (const float*)d_in[5];
    float* out = (float*)d_out;

    char* ws = (char*)d_ws;
    bf16*  featbf = (bf16*)(ws + FEAT_OFF);
    bf16*  omwr   = (bf16*)(ws + OMW_OFF);
    float* ombr   = (float*)(ws + OMB_OFF);
    bf16*  dcbf   = (bf16*)(ws + DCW_OFF);

    prep_cvt<<<(4194304 + 255) / 256, 256, 0, stream>>>(feat, featbf, 4194304);
    prep_w<<<(995328 + 255) / 256, 256, 0, stream>>>(om_w, om_b, omwr, ombr);
    prep_cvt<<<(36864 + 255) / 256, 256, 0, stream>>>(dc_w, dcbf, 36864);

    deform_fused<<<512, 256, 0, stream>>>(inputs, featbf, omwr, ombr, dcbf, dc_b, out);
}